// Round 5
// baseline (37.351 us; speedup 1.0000x reference)
//
#include <hip/hip_runtime.h>

typedef __attribute__((ext_vector_type(4))) float  f32x4;
typedef __attribute__((ext_vector_type(8))) short  short8;
typedef __attribute__((ext_vector_type(4))) unsigned int u32x4;
typedef __attribute__((ext_vector_type(2))) unsigned int u32x2;

#define NN 200
#define EDIM 128
#define FDIM 16
#define BN_TOTAL 1600
#define NCHUNK 7                 // m-chunks of 32 rows
#define MSG_BLOCKS 2800          // 4 items per 64-thread (1-wave) block
#define LAMBDA 2.8853900817779268f   // 2*log2(e): exp2(LAMBDA*x) = e^{2x}

// ws layout (regions passed as separate __restrict__ pointers):
// shorts: [0,2048) W_edge*L, [2048,2176) W_weight*L, [2176,18560) W_out
// floats: [10240, 215040) hi*L [1600][128]; [215040, ...) part [7][1600][128]
#define WS_WOUT_S 2176
#define WSF_HI    10240
#define WSF_PART  215040

__device__ __forceinline__ unsigned short f2bf(float f) {
    unsigned u = __float_as_uint(f);
    u += 0x7FFFu + ((u >> 16) & 1u);   // RNE
    return (unsigned short)(u >> 16);
}
__device__ __forceinline__ short8 cvt8(f32x4 a, f32x4 b) {
    short8 r;
    r[0]=(short)f2bf(a.x); r[1]=(short)f2bf(a.y); r[2]=(short)f2bf(a.z); r[3]=(short)f2bf(a.w);
    r[4]=(short)f2bf(b.x); r[5]=(short)f2bf(b.y); r[6]=(short)f2bf(b.z); r[7]=(short)f2bf(b.w);
    return r;
}
__device__ __forceinline__ unsigned cvtpk(float lo, float hi) {
    unsigned r;
    asm("v_cvt_pk_bf16_f32 %0, %1, %2" : "=v"(r) : "v"(lo), "v"(hi));
    return r;
}
// rcp(1 + exp2(x)); x = LAMBDA*arg -> equals 1/(1+e^{2 arg}); tanh = 1 - 2*this
__device__ __forceinline__ float sigr(float x) {
    return __builtin_amdgcn_rcpf(1.0f + __builtin_amdgcn_exp2f(x));
}

// ---------------------------------------------------------------------------
// setup: blocks 0..199 -> hi = LAMBDA * (h @ W_node^T)   (16 rows x 64 e each)
//        blocks 200..207 -> bf16 convert of weights (W_edge/W_weight scaled)
// ---------------------------------------------------------------------------
__global__ __launch_bounds__(128) void setup_kernel(
    const float* __restrict__ h, const float* __restrict__ W_node,
    const float* __restrict__ W_edge, const float* __restrict__ W_weight,
    const float* __restrict__ W_out,
    unsigned short* __restrict__ wcvt,   // W_edge(0..2047) + W_weight(2048..2175)
    unsigned short* __restrict__ wout,   // W_out bf16 [128][128]
    float* __restrict__ hi_arr)          // [1600][128]
{
    const int blk = blockIdx.x;
    const int tid = threadIdx.x;

    if (blk < 200) {
        const int rb   = blk >> 1;
        const int eh   = blk & 1;
        const int lane = tid & 63;
        const int w    = tid >> 6;        // 0..1
        const int g    = lane >> 4;
        const int l15  = lane & 15;
        const int r0   = rb * 16;

        short8 afr[4];
#pragma unroll
        for (int ks = 0; ks < 4; ++ks) {
            const float* p = h + (size_t)(r0 + l15) * EDIM + ks * 32 + g * 8;
            afr[ks] = cvt8(*(const f32x4*)p, *(const f32x4*)(p + 4));
        }
#pragma unroll
        for (int e2 = 0; e2 < 2; ++e2) {
            const int et = eh * 4 + w * 2 + e2;
            f32x4 acc = {0.f, 0.f, 0.f, 0.f};
#pragma unroll
            for (int ks = 0; ks < 4; ++ks) {
                const float* p = W_node + (size_t)(et * 16 + l15) * EDIM + ks * 32 + g * 8;
                short8 bfr = cvt8(*(const f32x4*)p, *(const f32x4*)(p + 4));
                acc = __builtin_amdgcn_mfma_f32_16x16x32_bf16(afr[ks], bfr, acc, 0, 0, 0);
            }
#pragma unroll
            for (int r = 0; r < 4; ++r)
                hi_arr[(size_t)(r0 + g * 4 + r) * EDIM + et * 16 + l15] = acc[r] * LAMBDA;
        }
    } else {
        // 4640 f32x4 chunks: [0,512) W_edge*L, [512,544) W_weight*L, [544,4640) W_out
        for (int c = (blk - 200) * 128 + tid; c < 4640; c += 8 * 128) {
            const float* src; unsigned short* dst; float sc;
            if (c < 512)      { src = W_edge   + c * 4;         dst = wcvt + c * 4;               sc = LAMBDA; }
            else if (c < 544) { src = W_weight + (c - 512) * 4; dst = wcvt + 2048 + (c - 512) * 4; sc = LAMBDA; }
            else              { src = W_out    + (c - 544) * 4; dst = wout + (c - 544) * 4;        sc = 1.0f; }
            f32x4 v = *(const f32x4*)src;
            v.x *= sc; v.y *= sc; v.z *= sc; v.w *= sc;
            u32x2 pk = { (unsigned)f2bf(v.x) | ((unsigned)f2bf(v.y) << 16),
                         (unsigned)f2bf(v.z) | ((unsigned)f2bf(v.w) << 16) };
            *(u32x2*)dst = pk;
        }
    }
}

// ---------------------------------------------------------------------------
// msg: 2800 single-wave blocks x 4 items; item = (bn, cj) = 32 m-rows.
// Register-double-buffered pipeline; branch-free body (poison K-channel
// k17: A=1 on pad rows, B=2^20 -> exp2 -> inf -> rcp -> 0 contribution).
// part[cj][bn][e] = sum over the chunk's valid rows of rcp(1+exp2(c)).
// ---------------------------------------------------------------------------
#define LOAD_ITEM(BE, BH, BN, CJ)                                             \
  do {                                                                        \
    _Pragma("unroll")                                                         \
    for (int t_ = 0; t_ < 2; ++t_) {                                          \
      int row_  = (CJ) * 32 + t_ * 16 + l15;                                  \
      int rowc_ = row_ > NN - 1 ? NN - 1 : row_;                              \
      if (g < 2) {                                                            \
        const float* p_ = ef + ((size_t)(BN) * NN + rowc_) * FDIM + g * 8;    \
        BE[t_ * 2]     = *(const f32x4*)p_;                                   \
        BE[t_ * 2 + 1] = *(const f32x4*)(p_ + 4);                             \
      } else if (g == 2) {                                                    \
        BE[t_ * 2].x = Wadj[(BN) * NN + rowc_];                               \
      }                                                                       \
    }                                                                         \
    _Pragma("unroll")                                                         \
    for (int et_ = 0; et_ < 8; ++et_)                                         \
      BH[et_] = hi_arr[(size_t)(BN) * EDIM + et_ * 16 + l15];                 \
  } while (0)

#define COMP_ITEM(BE, BH, BN, CJ)                                             \
  do {                                                                        \
    float Sr_[8];                                                             \
    _Pragma("unroll")                                                         \
    for (int et_ = 0; et_ < 8; ++et_) Sr_[et_] = 0.f;                         \
    _Pragma("unroll")                                                         \
    for (int t_ = 0; t_ < 2; ++t_) {                                          \
      short8 a_;                                                              \
      if (g < 2) {                                                            \
        u32x4 pk_ = { cvtpk(BE[t_*2].x,   BE[t_*2].y),                        \
                      cvtpk(BE[t_*2].z,   BE[t_*2].w),                        \
                      cvtpk(BE[t_*2+1].x, BE[t_*2+1].y),                      \
                      cvtpk(BE[t_*2+1].z, BE[t_*2+1].w) };                    \
        a_ = __builtin_bit_cast(short8, pk_);                                 \
      } else {                                                                \
        short8 z_ = {0,0,0,0,0,0,0,0};                                        \
        if (g == 2) {                                                         \
          z_[0] = (short)f2bf(BE[t_*2].x);                                    \
          if ((CJ) * 32 + t_ * 16 + l15 >= NN) z_[1] = (short)0x4980;         \
        }                                                                     \
        a_ = z_;                                                              \
      }                                                                       \
      _Pragma("unroll")                                                       \
      for (int et_ = 0; et_ < 8; ++et_) {                                     \
        f32x4 c_ = {BH[et_], BH[et_], BH[et_], BH[et_]};                      \
        c_ = __builtin_amdgcn_mfma_f32_16x16x32_bf16(a_, bfrag[et_], c_, 0, 0, 0); \
        Sr_[et_] += sigr(c_[0]) + sigr(c_[1]) + sigr(c_[2]) + sigr(c_[3]);    \
      }                                                                       \
    }                                                                         \
    _Pragma("unroll")                                                         \
    for (int et_ = 0; et_ < 8; ++et_) {                                       \
      float p_ = Sr_[et_];                                                    \
      p_ += __shfl_xor(p_, 16);                                               \
      p_ += __shfl_xor(p_, 32);                                               \
      Sr_[et_] = p_;                                                          \
    }                                                                         \
    if (g == 0) {                                                             \
      float* dst_ = part + ((size_t)(CJ) * BN_TOTAL + (BN)) * EDIM + l15;     \
      _Pragma("unroll")                                                       \
      for (int et_ = 0; et_ < 8; ++et_) dst_[et_ * 16] = Sr_[et_];            \
    }                                                                         \
  } while (0)

__global__ __launch_bounds__(64) void msg_kernel(
    const float* __restrict__ ef, const float* __restrict__ Wadj,
    const unsigned short* __restrict__ wcvt,   // W_edge*L + W_weight*L
    const float* __restrict__ hi_arr,          // LAMBDA*hi
    float* __restrict__ part)                  // [7][1600][128]
{
    const int lane = threadIdx.x;
    const int g    = lane >> 4;
    const int l15  = lane & 15;

    // persistent B fragments: k<16 = L*W_edge[e][k]; k16 = L*W_weight[e];
    // k17 = 2^20 (poison channel); rest 0
    short8 bfrag[8];
#pragma unroll
    for (int et = 0; et < 8; ++et) {
        short8 b = {0, 0, 0, 0, 0, 0, 0, 0};
        if (g < 2) b = *(const short8*)(wcvt + (et * 16 + l15) * FDIM + g * 8);
        else if (g == 2) {
            b[0] = (short)wcvt[2048 + et * 16 + l15];
            b[1] = (short)0x4980;                      // bf16 2^20
        }
        bfrag[et] = b;
    }

    const int idx = blockIdx.x * 4;
    int bn_[4], cj_[4];
#pragma unroll
    for (int k = 0; k < 4; ++k) {
        int id = idx + k;
        int b  = (id * 18725) >> 17;                   // id/7 for id < 43690
        bn_[k] = b; cj_[k] = id - b * 7;
    }

    f32x4 beA[4], beB[4];
    float bhA[8], bhB[8];

    LOAD_ITEM(beA, bhA, bn_[0], cj_[0]);
    LOAD_ITEM(beB, bhB, bn_[1], cj_[1]);
    COMP_ITEM(beA, bhA, bn_[0], cj_[0]);
    LOAD_ITEM(beA, bhA, bn_[2], cj_[2]);
    COMP_ITEM(beB, bhB, bn_[1], cj_[1]);
    LOAD_ITEM(beB, bhB, bn_[3], cj_[3]);
    COMP_ITEM(beA, bhA, bn_[2], cj_[2]);
    COMP_ITEM(beB, bhB, bn_[3], cj_[3]);
}

// ---------------------------------------------------------------------------
// outproj: 200 blocks x 128 thr; block = 16 bn-rows x 64 f-cols.
// agg[e] = 1 - 0.01 * sum_j part[j][bn][e];  out = agg @ W_out^T + b_out.
// ---------------------------------------------------------------------------
__global__ __launch_bounds__(128) void outproj_kernel(
    const float* __restrict__ part, const unsigned short* __restrict__ wout,
    const float* __restrict__ b_out, float* __restrict__ out)
{
    const int tid  = threadIdx.x;
    const int lane = tid & 63;
    const int w    = tid >> 6;
    const int g    = lane >> 4;
    const int l15  = lane & 15;
    const int rb   = blockIdx.x >> 1;
    const int fh   = blockIdx.x & 1;
    const int r0   = rb * 16;

    short8 afr[4];
#pragma unroll
    for (int ks = 0; ks < 4; ++ks) {
        const size_t off = (size_t)(r0 + l15) * EDIM + ks * 32 + g * 8;
        f32x4 s0 = {0.f, 0.f, 0.f, 0.f}, s1 = {0.f, 0.f, 0.f, 0.f};
#pragma unroll
        for (int j = 0; j < NCHUNK; ++j) {
            const float* p = part + (size_t)j * (BN_TOTAL * EDIM) + off;
            s0 += *(const f32x4*)p;
            s1 += *(const f32x4*)(p + 4);
        }
        f32x4 a0, a1;
        a0.x = __builtin_fmaf(-0.01f, s0.x, 1.0f);
        a0.y = __builtin_fmaf(-0.01f, s0.y, 1.0f);
        a0.z = __builtin_fmaf(-0.01f, s0.z, 1.0f);
        a0.w = __builtin_fmaf(-0.01f, s0.w, 1.0f);
        a1.x = __builtin_fmaf(-0.01f, s1.x, 1.0f);
        a1.y = __builtin_fmaf(-0.01f, s1.y, 1.0f);
        a1.z = __builtin_fmaf(-0.01f, s1.z, 1.0f);
        a1.w = __builtin_fmaf(-0.01f, s1.w, 1.0f);
        afr[ks] = cvt8(a0, a1);
    }
#pragma unroll
    for (int f2 = 0; f2 < 2; ++f2) {
        const int ft = fh * 4 + w * 2 + f2;
        f32x4 acc = {0.f, 0.f, 0.f, 0.f};
#pragma unroll
        for (int ks = 0; ks < 4; ++ks) {
            short8 b = *(const short8*)(wout + (ft * 16 + l15) * EDIM + ks * 32 + g * 8);
            acc = __builtin_amdgcn_mfma_f32_16x16x32_bf16(afr[ks], b, acc, 0, 0, 0);
        }
        const float bo = b_out[ft * 16 + l15];
#pragma unroll
        for (int r = 0; r < 4; ++r)
            out[(size_t)(r0 + g * 4 + r) * EDIM + ft * 16 + l15] = acc[r] + bo;
    }
}

extern "C" void kernel_launch(void* const* d_in, const int* in_sizes, int n_in,
                              void* d_out, int out_size, void* d_ws, size_t ws_size,
                              hipStream_t stream) {
    const float* h        = (const float*)d_in[0];
    const float* ef       = (const float*)d_in[1];
    const float* W        = (const float*)d_in[2];
    const float* W_node   = (const float*)d_in[3];
    const float* W_edge   = (const float*)d_in[4];
    const float* W_weight = (const float*)d_in[5];
    const float* W_out    = (const float*)d_in[6];
    const float* b_out    = (const float*)d_in[7];
    float* out = (float*)d_out;

    unsigned short* wsb = (unsigned short*)d_ws;
    float*          wsf = (float*)d_ws;
    unsigned short* wcvt   = wsb;              // W_edge + W_weight (bf16, *LAMBDA)
    unsigned short* wout   = wsb + WS_WOUT_S;  // W_out bf16
    float*          hi_arr = wsf + WSF_HI;     // LAMBDA*hi
    float*          part   = wsf + WSF_PART;   // [7][1600][128]

    setup_kernel<<<208, 128, 0, stream>>>(h, W_node, W_edge, W_weight, W_out,
                                          wcvt, wout, hi_arr);
    msg_kernel<<<MSG_BLOCKS, 64, 0, stream>>>(ef, W, wcvt, hi_arr, part);
    outproj_kernel<<<200, 128, 0, stream>>>(part, wout, b_out, out);
}